// Round 1
// baseline (2131.059 us; speedup 1.0000x reference)
//
#include <hip/hip_runtime.h>

#define NROWS 2048
#define DR2   512
#define TSTEPS 64

typedef _Float16 half8 __attribute__((ext_vector_type(8)));
typedef float floatx4 __attribute__((ext_vector_type(4)));

// XOR-swizzled LDS index (units of _Float16). Row stride 64 halves = 128 B;
// swizzle the 16B-chunk index by (row & 7) so fragment reads (fixed chunk,
// rows 0..15 per quad) hit each bank group with only 2-way aliasing (free).
static __device__ __forceinline__ int sw_idx(int r, int c8) {
    return r * 64 + ((c8 ^ (r & 7)) << 3);
}

// Wt[j][kk] = w1[kk][j], f16, j in [0,512), kk in [0,1024).
// Write-coalesced; reads of w1 columns hit L2 after first touch (w1 = 2 MB).
__global__ void prep_w(const float* __restrict__ w1, _Float16* __restrict__ Wt) {
    int idx = blockIdx.x * 256 + threadIdx.x;   // = j*1024 + kk
    int kk = idx & 1023;
    int j  = idx >> 10;
    Wt[idx] = (_Float16)w1[kk * DR2 + j];
}

// h16[0] = (f16)h0 ; out0[0] = h0 (reference stores h0, NOT states[0])
__global__ void prep_h0(const float* __restrict__ h0, _Float16* __restrict__ h16,
                        float* __restrict__ out0) {
    int idx = blockIdx.x * 256 + threadIdx.x;   // per float4
    float4 v = ((const float4*)h0)[idx];
    ((float4*)out0)[idx] = v;
    union { uint2 u; _Float16 h[4]; } p;
    p.h[0] = (_Float16)v.x; p.h[1] = (_Float16)v.y;
    p.h[2] = (_Float16)v.z; p.h[3] = (_Float16)v.w;
    ((uint2*)h16)[idx] = p.u;
}

// One recurrence step: mm = [h_prev, static_t] @ w1 ; gate ; write outputs.
// Tile 64x64 per WG, 4 waves in 2x2, each wave 32x32 via 2x2 mfma 16x16x32 f16.
__global__ __launch_bounds__(256) void step_kernel(
    const float* __restrict__ sta,      // [T,N,512] f32
    const float* __restrict__ thr,      // [T,N] f32
    const _Float16* __restrict__ Wt,    // [512][1024] f16 (B^T layout)
    const _Float16* __restrict__ hprev, // [N,512] f16
    _Float16* __restrict__ hnext,       // [N,512] f16
    float* __restrict__ out0,           // [T,N,512]
    float* __restrict__ out1,           // [N,512]
    float* __restrict__ out2,           // [T-1,N,512]
    int t)
{
    __shared__ _Float16 Ash[64 * 64];
    __shared__ _Float16 Bsh[64 * 64];
    const int tid   = threadIdx.x;
    const int lane  = tid & 63;
    const int wv    = tid >> 6;
    const int waveM = wv & 1;
    const int waveJ = wv >> 1;
    const int n0 = blockIdx.y * 64;
    const int j0 = blockIdx.x * 64;
    const int sr  = tid >> 3;   // staging row 0..31 (and +32)
    const int sc8 = tid & 7;    // staging 16B-chunk col 0..7

    floatx4 acc[2][2] = {};

    for (int kk0 = 0; kk0 < 1024; kk0 += 64) {
        __syncthreads();
        // ---- stage B tile: Bsh[j][k] = Wt[(j0+j)][kk0+k] (already f16, B^T) ----
        {
            const _Float16* s1 = Wt + (j0 + sr) * 1024 + kk0 + sc8 * 8;
            *(float4*)(Bsh + sw_idx(sr, sc8))      = *(const float4*)s1;
            *(float4*)(Bsh + sw_idx(sr + 32, sc8)) = *(const float4*)(s1 + 32 * 1024);
        }
        // ---- stage A tile: rows are n; k<512 from h16, k>=512 from static f32 ----
        if (kk0 < 512) {
            const _Float16* s1 = hprev + (n0 + sr) * 512 + kk0 + sc8 * 8;
            *(float4*)(Ash + sw_idx(sr, sc8))      = *(const float4*)s1;
            *(float4*)(Ash + sw_idx(sr + 32, sc8)) = *(const float4*)(s1 + 32 * 512);
        } else {
            size_t base = ((size_t)(t * NROWS + n0 + sr)) * 512 + (kk0 - 512) + sc8 * 8;
            float4 lo = *(const float4*)(sta + base);
            float4 hi = *(const float4*)(sta + base + 4);
            union { float4 v; _Float16 h[8]; } u;
            u.h[0]=(_Float16)lo.x; u.h[1]=(_Float16)lo.y; u.h[2]=(_Float16)lo.z; u.h[3]=(_Float16)lo.w;
            u.h[4]=(_Float16)hi.x; u.h[5]=(_Float16)hi.y; u.h[6]=(_Float16)hi.z; u.h[7]=(_Float16)hi.w;
            *(float4*)(Ash + sw_idx(sr, sc8)) = u.v;
            float4 lo2 = *(const float4*)(sta + base + 32 * 512);
            float4 hi2 = *(const float4*)(sta + base + 32 * 512 + 4);
            u.h[0]=(_Float16)lo2.x; u.h[1]=(_Float16)lo2.y; u.h[2]=(_Float16)lo2.z; u.h[3]=(_Float16)lo2.w;
            u.h[4]=(_Float16)hi2.x; u.h[5]=(_Float16)hi2.y; u.h[6]=(_Float16)hi2.z; u.h[7]=(_Float16)hi2.w;
            *(float4*)(Ash + sw_idx(sr + 32, sc8)) = u.v;
        }
        __syncthreads();

        // ---- MFMA over the two 32-wide k-steps in this BK=64 chunk ----
        const int lm   = lane & 15;
        const int quad = lane >> 4;
        #pragma unroll
        for (int ks = 0; ks < 2; ++ks) {
            int c8 = ks * 4 + quad;   // k offset = ks*32 + quad*8
            half8 a0 = *(const half8*)(Ash + sw_idx(waveM * 32 + lm,      c8));
            half8 a1 = *(const half8*)(Ash + sw_idx(waveM * 32 + 16 + lm, c8));
            half8 b0 = *(const half8*)(Bsh + sw_idx(waveJ * 32 + lm,      c8));
            half8 b1 = *(const half8*)(Bsh + sw_idx(waveJ * 32 + 16 + lm, c8));
            acc[0][0] = __builtin_amdgcn_mfma_f32_16x16x32_f16(a0, b0, acc[0][0], 0, 0, 0);
            acc[0][1] = __builtin_amdgcn_mfma_f32_16x16x32_f16(a0, b1, acc[0][1], 0, 0, 0);
            acc[1][0] = __builtin_amdgcn_mfma_f32_16x16x32_f16(a1, b0, acc[1][0], 0, 0, 0);
            acc[1][1] = __builtin_amdgcn_mfma_f32_16x16x32_f16(a1, b1, acc[1][1], 0, 0, 0);
        }
    }

    // ---- epilogue: gate + writes. C/D layout: col = lane&15, row = quad*4+reg ----
    const int quad = lane >> 4;
    const int lj   = lane & 15;
    const float DECAY = 0.60653065971263342f;
    #pragma unroll
    for (int tm = 0; tm < 2; ++tm) {
        #pragma unroll
        for (int r = 0; r < 4; ++r) {
            int n = n0 + waveM * 32 + tm * 16 + quad * 4 + r;
            float thv = thr[t * NROWS + n];
            float om  = 1.0f - thv;
            #pragma unroll
            for (int tj = 0; tj < 2; ++tj) {
                int j = j0 + waveJ * 32 + tj * 16 + lj;
                float hp = (float)hprev[n * 512 + j];
                float z  = acc[tm][tj][r] * thv + hp * om;
                float hn = DECAY / (1.0f + __expf(-z));
                hnext[n * 512 + j] = (_Float16)hn;
                if (t >= 1) {
                    size_t o = ((size_t)t * NROWS + n) * 512 + j;
                    out0[o] = hn;
                    out2[o - (size_t)NROWS * 512] = hn - hp;  // slice t-1
                }
                if (t == 63) out1[n * 512 + j] = hn;
            }
        }
    }
}

extern "C" void kernel_launch(void* const* d_in, const int* in_sizes, int n_in,
                              void* d_out, int out_size, void* d_ws, size_t ws_size,
                              hipStream_t stream) {
    const float* d_static = (const float*)d_in[0];  // [64,2048,512]
    const float* d_thr    = (const float*)d_in[1];  // [64,2048,1]
    const float* d_h0     = (const float*)d_in[2];  // [2048,512]
    const float* d_w1     = (const float*)d_in[3];  // [1024,512]

    float* out0 = (float*)d_out;                               // [64,2048,512]
    float* out1 = out0 + (size_t)TSTEPS * NROWS * DR2;         // [2048,512]
    float* out2 = out1 + (size_t)NROWS * DR2;                  // [63,2048,512]

    // ws layout: Wt (1 MB) | h16 ping (2 MB) | h16 pong (2 MB)  -> 5 MB total
    _Float16* Wt    = (_Float16*)d_ws;
    _Float16* hbuf0 = Wt + 512 * 1024;
    _Float16* hbuf1 = hbuf0 + (size_t)NROWS * DR2;

    prep_w<<<2048, 256, 0, stream>>>(d_w1, Wt);
    prep_h0<<<1024, 256, 0, stream>>>(d_h0, hbuf0, out0);

    dim3 grid(8, 32);  // 8 col-blocks x 32 row-blocks, 64x64 tiles
    for (int t = 0; t < TSTEPS; ++t) {
        const _Float16* hp = (t & 1) ? hbuf1 : hbuf0;
        _Float16*       hn = (t & 1) ? hbuf0 : hbuf1;
        step_kernel<<<grid, 256, 0, stream>>>(d_static, d_thr, Wt, hp, hn,
                                              out0, out1, out2, t);
    }
}

// Round 2
// 1730.616 us; speedup vs baseline: 1.2314x; 1.2314x over previous
//
#include <hip/hip_runtime.h>

#define NROWS 2048
#define DR2   512
#define TSTEPS 64
#define KTOT  1024
#define KPH   256

typedef _Float16 half8 __attribute__((ext_vector_type(8)));
typedef float floatx4 __attribute__((ext_vector_type(4)));

// Async global->LDS, 16 B per lane. LDS base must be wave-uniform; HW writes
// lane i at base + i*16. Per-lane GLOBAL addresses are free -> we do the
// bank-conflict swizzle on the global-address side.
static __device__ __forceinline__ void gload_lds16(const _Float16* g, _Float16* l) {
    __builtin_amdgcn_global_load_lds(
        (const __attribute__((address_space(1))) unsigned int*)g,
        (__attribute__((address_space(3))) unsigned int*)l,
        16, 0, 0);
}

// Wt[j][kk] = w1[kk][j], f16.
__global__ void prep_w(const float* __restrict__ w1, _Float16* __restrict__ Wt) {
    int idx = blockIdx.x * 256 + threadIdx.x;   // = j*1024 + kk
    int kk = idx & 1023;
    int j  = idx >> 10;
    Wt[idx] = (_Float16)w1[kk * DR2 + j];
}

// h16 = (f16)h0 ; out0[0] = h0 (reference stores h0, NOT states[0])
__global__ void prep_h0(const float* __restrict__ h0, _Float16* __restrict__ h16,
                        float* __restrict__ out0) {
    int idx = blockIdx.x * 256 + threadIdx.x;   // per float4
    float4 v = ((const float4*)h0)[idx];
    ((float4*)out0)[idx] = v;
    union { uint2 u; _Float16 h[4]; } p;
    p.h[0] = (_Float16)v.x; p.h[1] = (_Float16)v.y;
    p.h[2] = (_Float16)v.z; p.h[3] = (_Float16)v.w;
    ((uint2*)h16)[idx] = p.u;
}

// One recurrence step. 64x64 tile/WG, 4 waves (2x2 of 32x32 via mfma 16x16x32).
// K=1024 consumed in 4 phases of 256: big staging burst -> 1 barrier -> MFMA.
// LDS element (row r, 16B-chunk c8) lives at halfword off r*KPH + ((c8^(r&7))<<3):
// 2-way max bank aliasing on fragment reads (free), conflict-free staging.
__global__ __launch_bounds__(256) void step_kernel(
    const float* __restrict__ sta,      // [T,N,512] f32
    const float* __restrict__ thr,      // [T,N] f32
    const _Float16* __restrict__ Wt,    // [512][1024] f16 (B^T)
    const _Float16* __restrict__ hprev, // [N,512] f16
    _Float16* __restrict__ hnext,       // [N,512] f16
    float* __restrict__ out0, float* __restrict__ out1, float* __restrict__ out2,
    int t)
{
    __shared__ _Float16 Ash[64 * KPH];  // 32 KB
    __shared__ _Float16 Bsh[64 * KPH];  // 32 KB

    const int tid   = threadIdx.x;
    const int lane  = tid & 63;
    const int wv    = tid >> 6;
    const int waveM = wv & 1;
    const int waveJ = wv >> 1;
    const int n0 = blockIdx.y * 64;
    const int j0 = blockIdx.x * 64;
    const int lm   = lane & 15;
    const int quad = lane >> 4;
    const int l32  = lane & 31;
    const int lr   = lane >> 5;

    floatx4 acc[2][2] = {};

    for (int ph = 0; ph < 4; ++ph) {
        __syncthreads();
        // ---- B tile: 64 j-rows x 256 k, f16 via global_load_lds ----
        #pragma unroll
        for (int i = 0; i < 8; ++i) {
            int rp = (wv * 8 + i) * 2;          // row-pair base (wave-uniform)
            int r  = rp + lr;
            int k8 = l32 ^ (r & 7);
            gload_lds16(Wt + (size_t)(j0 + r) * KTOT + ph * KPH + k8 * 8,
                        Bsh + rp * KPH);
        }
        if (ph < 2) {
            // ---- A tile from h (f16) via global_load_lds ----
            #pragma unroll
            for (int i = 0; i < 8; ++i) {
                int rp = (wv * 8 + i) * 2;
                int r  = rp + lr;
                int k8 = l32 ^ (r & 7);
                gload_lds16(hprev + (size_t)(n0 + r) * DR2 + ph * KPH + k8 * 8,
                            Ash + rp * KPH);
            }
        } else {
            // ---- A tile from static (f32): load + cvt + swizzled ds_write ----
            #pragma unroll
            for (int p = 0; p < 8; ++p) {
                int c   = p * 256 + tid;        // chunk id 0..2047
                int r   = c >> 5;
                int c8p = c & 31;
                int k8  = c8p ^ (r & 7);
                size_t g = ((size_t)(t * NROWS + n0 + r)) * DR2 + (ph - 2) * KPH + k8 * 8;
                float4 lo = *(const float4*)(sta + g);
                float4 hi = *(const float4*)(sta + g + 4);
                union { half8 v; _Float16 h[8]; } u;
                u.h[0]=(_Float16)lo.x; u.h[1]=(_Float16)lo.y;
                u.h[2]=(_Float16)lo.z; u.h[3]=(_Float16)lo.w;
                u.h[4]=(_Float16)hi.x; u.h[5]=(_Float16)hi.y;
                u.h[6]=(_Float16)hi.z; u.h[7]=(_Float16)hi.w;
                *(half8*)(Ash + r * KPH + (c8p << 3)) = u.v;
            }
        }
        __syncthreads();

        // ---- compute: 8 ksteps x 4 MFMA ----
        const int ra0 = waveM * 32 + lm, ra1 = ra0 + 16;
        const int rb0 = waveJ * 32 + lm, rb1 = rb0 + 16;
        #pragma unroll
        for (int ks = 0; ks < 8; ++ks) {
            int c8 = ks * 4 + quad;
            half8 a0 = *(const half8*)(Ash + ra0 * KPH + (((c8 ^ (ra0 & 7))) << 3));
            half8 a1 = *(const half8*)(Ash + ra1 * KPH + (((c8 ^ (ra1 & 7))) << 3));
            half8 b0 = *(const half8*)(Bsh + rb0 * KPH + (((c8 ^ (rb0 & 7))) << 3));
            half8 b1 = *(const half8*)(Bsh + rb1 * KPH + (((c8 ^ (rb1 & 7))) << 3));
            acc[0][0] = __builtin_amdgcn_mfma_f32_16x16x32_f16(a0, b0, acc[0][0], 0, 0, 0);
            acc[0][1] = __builtin_amdgcn_mfma_f32_16x16x32_f16(a0, b1, acc[0][1], 0, 0, 0);
            acc[1][0] = __builtin_amdgcn_mfma_f32_16x16x32_f16(a1, b0, acc[1][0], 0, 0, 0);
            acc[1][1] = __builtin_amdgcn_mfma_f32_16x16x32_f16(a1, b1, acc[1][1], 0, 0, 0);
        }
    }

    // ---- epilogue: gate + writes. C/D layout: col = lane&15, row = quad*4+reg ----
    const float DECAY = 0.60653065971263342f;
    #pragma unroll
    for (int tm = 0; tm < 2; ++tm) {
        #pragma unroll
        for (int r = 0; r < 4; ++r) {
            int n = n0 + waveM * 32 + tm * 16 + quad * 4 + r;
            float thv = thr[t * NROWS + n];
            float om  = 1.0f - thv;
            #pragma unroll
            for (int tj = 0; tj < 2; ++tj) {
                int j = j0 + waveJ * 32 + tj * 16 + lm;
                float hp = (float)hprev[n * DR2 + j];
                float z  = acc[tm][tj][r] * thv + hp * om;
                float hn = DECAY / (1.0f + __expf(-z));
                hnext[n * DR2 + j] = (_Float16)hn;
                if (t >= 1) {
                    size_t o = ((size_t)t * NROWS + n) * DR2 + j;
                    out0[o] = hn;
                    out2[o - (size_t)NROWS * DR2] = hn - hp;  // slice t-1
                }
                if (t == 63) out1[n * DR2 + j] = hn;
            }
        }
    }
}

extern "C" void kernel_launch(void* const* d_in, const int* in_sizes, int n_in,
                              void* d_out, int out_size, void* d_ws, size_t ws_size,
                              hipStream_t stream) {
    const float* d_static = (const float*)d_in[0];
    const float* d_thr    = (const float*)d_in[1];
    const float* d_h0     = (const float*)d_in[2];
    const float* d_w1     = (const float*)d_in[3];

    float* out0 = (float*)d_out;
    float* out1 = out0 + (size_t)TSTEPS * NROWS * DR2;
    float* out2 = out1 + (size_t)NROWS * DR2;

    _Float16* Wt    = (_Float16*)d_ws;                  // 1 MB
    _Float16* hbuf0 = Wt + (size_t)DR2 * KTOT;          // 2 MB
    _Float16* hbuf1 = hbuf0 + (size_t)NROWS * DR2;      // 2 MB

    prep_w<<<2048, 256, 0, stream>>>(d_w1, Wt);
    prep_h0<<<1024, 256, 0, stream>>>(d_h0, hbuf0, out0);

    dim3 grid(8, 32);
    for (int t = 0; t < TSTEPS; ++t) {
        const _Float16* hp = (t & 1) ? hbuf1 : hbuf0;
        _Float16*       hn = (t & 1) ? hbuf0 : hbuf1;
        step_kernel<<<grid, 256, 0, stream>>>(d_static, d_thr, Wt, hp, hn,
                                              out0, out1, out2, t);
    }
}

// Round 3
// 1293.244 us; speedup vs baseline: 1.6478x; 1.3382x over previous
//
#include <hip/hip_runtime.h>

#define NROWS 2048
#define DR2   512
#define TSTEPS 64
#define NK    ((size_t)NROWS * DR2)          // elements per [N,512] slice

typedef _Float16 half8 __attribute__((ext_vector_type(8)));
typedef float floatx4 __attribute__((ext_vector_type(4)));

// Async global->LDS, 16 B/lane. LDS base wave-uniform; HW scatters lane i at
// base + 16*i. Bank-conflict swizzle is applied on the GLOBAL address side.
static __device__ __forceinline__ void gload_lds16(const _Float16* g, _Float16* l) {
    __builtin_amdgcn_global_load_lds(
        (const __attribute__((address_space(1))) unsigned int*)g,
        (__attribute__((address_space(3))) unsigned int*)l,
        16, 0, 0);
}

// Wt[j][kk] = w1[kk][j], f16, j in [0,512), kk in [0,1024). Top half kk<512
// multiplies h; bottom half kk>=512 multiplies static.
__global__ void prep_w(const float* __restrict__ w1, _Float16* __restrict__ Wt) {
    int idx = blockIdx.x * 256 + threadIdx.x;   // = j*1024 + kk
    int kk = idx & 1023;
    int j  = idx >> 10;
    Wt[idx] = (_Float16)w1[kk * DR2 + j];
}

// h16 = (f16)h0 ; out0[0] = h0 (reference stores h0, NOT states[0])
__global__ void prep_h0(const float* __restrict__ h0, _Float16* __restrict__ h16,
                        float* __restrict__ out0) {
    int idx = blockIdx.x * 256 + threadIdx.x;   // per float4
    float4 v = ((const float4*)h0)[idx];
    ((float4*)out0)[idx] = v;
    union { uint2 u; _Float16 h[4]; } p;
    p.h[0] = (_Float16)v.x; p.h[1] = (_Float16)v.y;
    p.h[2] = (_Float16)v.z; p.h[3] = (_Float16)v.w;
    ((uint2*)h16)[idx] = p.u;
}

// S[t] = static_t @ w1_bot, all t at once: [131072,512] @ [512,512].
// 128x128 tiles, 4 waves (2x2 of 64x64), K=512 in 4 phases of 128.
// S[0] -> S0 (= out0 slice 1 overlay); S[t>=1] -> Srest[t-1] (= out2 overlay).
#define KPP 128
__global__ __launch_bounds__(256) void precompute_S(
    const float* __restrict__ sta, const _Float16* __restrict__ Wt,
    float* S0, float* Srest)
{
    __shared__ _Float16 Ash[128 * KPP];   // 32 KB
    __shared__ _Float16 Bsh[128 * KPP];   // 32 KB
    const int tid = threadIdx.x, lane = tid & 63, wv = tid >> 6;
    const int waveM = wv & 1, waveJ = wv >> 1;
    const int lm = lane & 15, quad = lane >> 4;
    const int j0  = blockIdx.x * 128;
    const int mr0 = blockIdx.y * 128;           // global row = t*2048 + n
    const int t  = mr0 >> 11;
    const int n0 = mr0 & 2047;

    floatx4 acc[4][4] = {};

    for (int ph = 0; ph < 4; ++ph) {
        __syncthreads();
        // B tile: Wt[j0+r][512 + ph*128 + k], r=0..127 (f16, async)
        #pragma unroll
        for (int i = 0; i < 8; ++i) {
            int rp = wv * 32 + i * 4;           // 4 rows per 1KB instruction
            int r  = rp + (lane >> 4);
            int k8 = (lane & 15) ^ (r & 7);
            gload_lds16(Wt + (size_t)(j0 + r) * 1024 + 512 + ph * KPP + k8 * 8,
                        Bsh + rp * KPP);
        }
        // A tile: static f32 -> f16, swizzled ds_write
        #pragma unroll
        for (int p = 0; p < 8; ++p) {
            int c = p * 256 + tid;              // 0..2047 = 128 rows x 16 chunks
            int r = c >> 4, c8p = c & 15;
            int k8 = c8p ^ (r & 7);
            size_t g = ((size_t)(mr0 + r)) * DR2 + ph * KPP + k8 * 8;
            float4 lo = *(const float4*)(sta + g);
            float4 hi = *(const float4*)(sta + g + 4);
            union { half8 v; _Float16 h[8]; } u;
            u.h[0]=(_Float16)lo.x; u.h[1]=(_Float16)lo.y;
            u.h[2]=(_Float16)lo.z; u.h[3]=(_Float16)lo.w;
            u.h[4]=(_Float16)hi.x; u.h[5]=(_Float16)hi.y;
            u.h[6]=(_Float16)hi.z; u.h[7]=(_Float16)hi.w;
            *(half8*)(Ash + r * KPP + (c8p << 3)) = u.v;
        }
        __syncthreads();

        #pragma unroll
        for (int ks = 0; ks < 4; ++ks) {
            int c8 = ks * 4 + quad;             // chunk 0..15
            half8 a[4], b[4];
            #pragma unroll
            for (int tm = 0; tm < 4; ++tm) {
                int ra = waveM * 64 + tm * 16 + lm;
                a[tm] = *(const half8*)(Ash + ra * KPP + (((c8 ^ (ra & 7))) << 3));
            }
            #pragma unroll
            for (int tj = 0; tj < 4; ++tj) {
                int rb = waveJ * 64 + tj * 16 + lm;
                b[tj] = *(const half8*)(Bsh + rb * KPP + (((c8 ^ (rb & 7))) << 3));
            }
            #pragma unroll
            for (int tm = 0; tm < 4; ++tm)
                #pragma unroll
                for (int tj = 0; tj < 4; ++tj)
                    acc[tm][tj] = __builtin_amdgcn_mfma_f32_16x16x32_f16(
                        a[tm], b[tj], acc[tm][tj], 0, 0, 0);
        }
    }

    float* dst = (t == 0) ? S0 : (Srest + (size_t)(t - 1) * NK);
    #pragma unroll
    for (int tm = 0; tm < 4; ++tm) {
        #pragma unroll
        for (int r = 0; r < 4; ++r) {
            int n = n0 + waveM * 64 + tm * 16 + quad * 4 + r;
            #pragma unroll
            for (int tj = 0; tj < 4; ++tj) {
                int j = j0 + waveJ * 64 + tj * 16 + lm;
                dst[(size_t)n * DR2 + j] = acc[tm][tj][r];
            }
        }
    }
}

// Sequential step: mm = h @ Wtop + S[t]; gate; outputs.
// 32x64 tile, grid (8,64)=512 WGs (2 WG/CU), K=512 in 2 phases of 256.
// S/out0/out2 alias (overlay) -> NOT __restrict__; S read up-front.
__global__ __launch_bounds__(256) void step_kernel(
    const float* __restrict__ thr,      // [T,N]
    const _Float16* __restrict__ Wt,    // [512][1024], top half used
    const _Float16* __restrict__ hprev, // [N,512] f16
    _Float16* __restrict__ hnext,       // [N,512] f16
    const float* S,                     // [N,512] slice (overlay)
    float* out0, float* __restrict__ out1, float* out2,
    int t)
{
    __shared__ _Float16 Ash[32 * 256];  // 16 KB
    __shared__ _Float16 Bsh[64 * 256];  // 32 KB
    const int tid = threadIdx.x, lane = tid & 63, wv = tid >> 6;
    const int waveM = wv & 1, waveJ = wv >> 1;
    const int lm = lane & 15, quad = lane >> 4;
    const int n0 = blockIdx.y * 32;
    const int j0 = blockIdx.x * 64;

    // ---- epilogue operand prefetch (hidden under the GEMM) ----
    const int nb = n0 + waveM * 16 + quad * 4;          // + r
    const int jb = j0 + waveJ * 32 + lm;                // + tj*16
    float thv[4], sv[2][4], hpv[2][4];
    #pragma unroll
    for (int r = 0; r < 4; ++r) {
        thv[r] = thr[t * NROWS + nb + r];
        #pragma unroll
        for (int tj = 0; tj < 2; ++tj) {
            size_t o = (size_t)(nb + r) * DR2 + jb + tj * 16;
            sv[tj][r]  = S[o];
            hpv[tj][r] = (float)hprev[o];
        }
    }

    floatx4 acc[2] = {};
    for (int ph = 0; ph < 2; ++ph) {
        __syncthreads();
        // B: Wtop[j0..j0+63][ph*256..+256] (f16 async, 2 rows/instr)
        #pragma unroll
        for (int i = 0; i < 8; ++i) {
            int rp = wv * 16 + i * 2;
            int r  = rp + (lane >> 5);
            int k8 = (lane & 31) ^ (r & 7);
            gload_lds16(Wt + (size_t)(j0 + r) * 1024 + ph * 256 + k8 * 8,
                        Bsh + rp * 256);
        }
        // A: h[n0..n0+31][ph*256..+256]
        #pragma unroll
        for (int i = 0; i < 4; ++i) {
            int rp = wv * 8 + i * 2;
            int r  = rp + (lane >> 5);
            int k8 = (lane & 31) ^ (r & 7);
            gload_lds16(hprev + (size_t)(n0 + r) * DR2 + ph * 256 + k8 * 8,
                        Ash + rp * 256);
        }
        __syncthreads();

        const int ra  = waveM * 16 + lm;
        const int rb0 = waveJ * 32 + lm, rb1 = rb0 + 16;
        #pragma unroll
        for (int ks = 0; ks < 8; ++ks) {
            int c8 = ks * 4 + quad;             // chunk 0..31
            half8 a  = *(const half8*)(Ash + ra  * 256 + (((c8 ^ (ra  & 7))) << 3));
            half8 b0 = *(const half8*)(Bsh + rb0 * 256 + (((c8 ^ (rb0 & 7))) << 3));
            half8 b1 = *(const half8*)(Bsh + rb1 * 256 + (((c8 ^ (rb1 & 7))) << 3));
            acc[0] = __builtin_amdgcn_mfma_f32_16x16x32_f16(a, b0, acc[0], 0, 0, 0);
            acc[1] = __builtin_amdgcn_mfma_f32_16x16x32_f16(a, b1, acc[1], 0, 0, 0);
        }
    }

    const float DECAY = 0.60653065971263342f;
    #pragma unroll
    for (int r = 0; r < 4; ++r) {
        int n = nb + r;
        float om = 1.0f - thv[r];
        #pragma unroll
        for (int tj = 0; tj < 2; ++tj) {
            int j = jb + tj * 16;
            float z  = (acc[tj][r] + sv[tj][r]) * thv[r] + hpv[tj][r] * om;
            float hn = DECAY / (1.0f + __expf(-z));
            hnext[(size_t)n * DR2 + j] = (_Float16)hn;
            if (t >= 1) {
                size_t o = ((size_t)t * NROWS + n) * DR2 + j;
                out0[o] = hn;
                out2[o - NK] = hn - hpv[tj][r];     // slice t-1 (overwrites S[t])
            }
            if (t == 63) out1[(size_t)n * DR2 + j] = hn;
        }
    }
}

extern "C" void kernel_launch(void* const* d_in, const int* in_sizes, int n_in,
                              void* d_out, int out_size, void* d_ws, size_t ws_size,
                              hipStream_t stream) {
    const float* d_static = (const float*)d_in[0];
    const float* d_thr    = (const float*)d_in[1];
    const float* d_h0     = (const float*)d_in[2];
    const float* d_w1     = (const float*)d_in[3];

    float* out0 = (float*)d_out;                       // [64,2048,512]
    float* out1 = out0 + (size_t)TSTEPS * NK;          // [2048,512]
    float* out2 = out1 + NK;                           // [63,2048,512]

    _Float16* Wt    = (_Float16*)d_ws;                 // 1 MB
    _Float16* hbuf0 = Wt + (size_t)DR2 * 1024;         // 2 MB
    _Float16* hbuf1 = hbuf0 + NK;                      // 2 MB

    float* S0 = out0 + NK;   // S[0] overlays out0 slice 1 (consumed at t=0,
                             // overwritten by the real out0[1] at t=1)

    prep_w<<<2048, 256, 0, stream>>>(d_w1, Wt);
    prep_h0<<<1024, 256, 0, stream>>>(d_h0, hbuf0, out0);
    precompute_S<<<dim3(4, 1024), 256, 0, stream>>>(d_static, Wt, S0, out2);

    dim3 grid(8, 64);
    for (int t = 0; t < TSTEPS; ++t) {
        const _Float16* hp = (t & 1) ? hbuf1 : hbuf0;
        _Float16*       hn = (t & 1) ? hbuf0 : hbuf1;
        const float*    S  = (t == 0) ? S0 : (out2 + (size_t)(t - 1) * NK);
        step_kernel<<<grid, 256, 0, stream>>>(d_thr, Wt, hp, hn, S,
                                              out0, out1, out2, t);
    }
}